// Round 19
// baseline (211.920 us; speedup 1.0000x reference)
//
#include <hip/hip_runtime.h>

// ---------- types ----------
typedef __attribute__((ext_vector_type(8)))  __bf16 bf16x8;
typedef __attribute__((ext_vector_type(4)))  __bf16 bf16x4;
typedef __attribute__((ext_vector_type(4)))  float  f32x4;
typedef __attribute__((ext_vector_type(16))) float  f32x16;
typedef __attribute__((ext_vector_type(4)))  unsigned int u32x4;

#define DEVINL __device__ __forceinline__

DEVINL void async_copy16(const __bf16* g, __bf16* l) {
  __builtin_amdgcn_global_load_lds(
      (__attribute__((address_space(1))) void*)(g),
      (__attribute__((address_space(3))) void*)(l), 16, 0, 0);
}

DEVINL unsigned int pack2(float a, float b) {
  unsigned short ua = __builtin_bit_cast(unsigned short, (__bf16)a);
  unsigned short ub = __builtin_bit_cast(unsigned short, (__bf16)b);
  return (unsigned int)ua | ((unsigned int)ub << 16);
}

// ---------- fused prologue: x cvt + both weight transposes, ONE dispatch ----
__global__ __launch_bounds__(256) void prep(
    const float* __restrict__ x, __bf16* __restrict__ xb,
    const float* __restrict__ Wqkv, __bf16* __restrict__ wqkvt,
    const float* __restrict__ Wout, __bf16* __restrict__ woutt) {
  const int id = blockIdx.x;
  if (id < 8192) {
    const int i = (id * 256 + threadIdx.x) * 4;
    const float4 f = *(const float4*)(x + i);
    bf16x4 ov;
    ov.x = (__bf16)f.x; ov.y = (__bf16)f.y;
    ov.z = (__bf16)f.z; ov.w = (__bf16)f.w;
    *(bf16x4*)(xb + i) = ov;
  } else {
    __shared__ float tile[32][33];
    const float* W;
    __bf16* Wt;
    int N, bx, by;
    if (id < 11264) {
      const int r = id - 8192;
      W = Wqkv; Wt = wqkvt; N = 3072; bx = r % 96; by = r / 96;
    } else {
      const int r = id - 11264;
      W = Wout; Wt = woutt; N = 1024; bx = r & 31; by = r >> 5;
    }
    const int tx = threadIdx.x & 31, ty = threadIdx.x >> 5;
    const int kb = by * 32, nb = bx * 32;
#pragma unroll
    for (int j = ty; j < 32; j += 8)
      tile[j][tx] = W[(size_t)(kb + j) * N + nb + tx];
    __syncthreads();
#pragma unroll
    for (int j = ty; j < 32; j += 8)
      Wt[(size_t)(nb + j) * 1024 + kb + tx] = (__bf16)tile[tx][j];
  }
}

// ---------- 8-wave 128x128 counted-vmcnt GEMM, phase-split compute ----------
// R12 schedule (verified) with compute(t) split into 4 barrier-separated
// sub-phases (per mq: {af+bfr0 reads; 4 MFMA}; barrier; {bfr1 reads; 4 MFMA};
// barrier). Staging position and vmcnt ladder UNCHANGED from R12: stage(t+2)
// issues only after the final sub-barrier (all reads of cur complete), so the
// R12 buffer audit holds verbatim. Phase-split creates {reads vs MFMA} wave
// diversity between barriers -> setprio arbitration active (T5/m218b).
template <int MODE, int XCDSWZ, int GX>
__global__ __launch_bounds__(512, 2) void gemmp8(
    const __bf16* __restrict__ A, const __bf16* __restrict__ Bt,
    __bf16* __restrict__ Qb, __bf16* __restrict__ Kb, __bf16* __restrict__ Vb,
    float* __restrict__ Cout, int K, int N) {
  constexpr int BM = 128, BN = 128;
  __shared__ __bf16 As[2][BM * 64];
  __shared__ __bf16 Bs[2][BN * 64];
  const int tid = threadIdx.x;
  const int lane = tid & 63;
  const int w = tid >> 6;
  const int wm = w >> 2, wn = w & 3;
  const int lr = lane & 15, lg = lane >> 4;

  int bx = blockIdx.x, by = blockIdx.y;
  if constexpr (XCDSWZ) {
    const int nwg = GX * gridDim.y;
    const int chunk = nwg >> 3;
    const int id = by * GX + bx;
    const int swz = (id & 7) * chunk + (id >> 3);
    bx = swz % GX;
    by = swz / GX;
  }
  const int row0 = by * BM;
  const int col0 = bx * BN;

  f32x4 acc[4][2] = {};

  auto stage = [&](int buf, int kt) {
    const int ko = kt * 64;
#pragma unroll
    for (int rd = 0; rd < 2; ++rd) {
      const int slot = rd * 512 + tid;
      const int r = slot >> 3, c = slot & 7;
      async_copy16(A + (size_t)(row0 + r) * K + ko + ((c ^ (r & 7)) << 3),
                   &As[buf][slot * 8]);
    }
#pragma unroll
    for (int rd = 0; rd < 2; ++rd) {
      const int slot = rd * 512 + tid;
      const int r = slot >> 3, c = slot & 7;
      async_copy16(Bt + (size_t)(col0 + r) * K + ko + ((c ^ (r & 7)) << 3),
                   &Bs[buf][slot * 8]);
    }
  };

  // one sub-phase: rows {wm*64 + (mq*2+{0,1})*16}, col group nq (16 cols)
  auto subphase = [&](int buf, int mq, int nq) {
    bf16x8 af[2][2], bfr[2];
#pragma unroll
    for (int mi2 = 0; mi2 < 2; ++mi2)
#pragma unroll
      for (int ks = 0; ks < 2; ++ks) {
        const int r = wm * 64 + (mq * 2 + mi2) * 16 + lr;
        af[mi2][ks] =
            *(const bf16x8*)(&As[buf][r * 64 + (((ks * 4 + lg) ^ (r & 7)) << 3)]);
      }
#pragma unroll
    for (int ks = 0; ks < 2; ++ks) {
      const int r = wn * 32 + nq * 16 + lr;
      bfr[ks] =
          *(const bf16x8*)(&Bs[buf][r * 64 + (((ks * 4 + lg) ^ (r & 7)) << 3)]);
    }
    __builtin_amdgcn_s_setprio(1);
#pragma unroll
    for (int mi2 = 0; mi2 < 2; ++mi2)
#pragma unroll
      for (int ks = 0; ks < 2; ++ks)
        acc[mq * 2 + mi2][nq] = __builtin_amdgcn_mfma_f32_16x16x32_bf16(
            af[mi2][ks], bfr[ks], acc[mq * 2 + mi2][nq], 0, 0, 0);
    __builtin_amdgcn_s_setprio(0);
  };

  const int nkt = K / 64;
  stage(0, 0);
  if (nkt > 1) stage(1, 1);
  int cur = 0;
#pragma unroll 1
  for (int t = 0; t < nkt; ++t) {
    if (t + 1 < nkt)
      asm volatile("s_waitcnt vmcnt(4)" ::: "memory");
    else
      asm volatile("s_waitcnt vmcnt(0)" ::: "memory");
    __builtin_amdgcn_s_barrier();
    asm volatile("" ::: "memory");
    subphase(cur, 0, 0);
    __builtin_amdgcn_s_barrier();
    subphase(cur, 0, 1);
    __builtin_amdgcn_s_barrier();
    subphase(cur, 1, 0);
    __builtin_amdgcn_s_barrier();
    subphase(cur, 1, 1);
    if (t + 2 < nkt) {
      __builtin_amdgcn_s_barrier();
      asm volatile("" ::: "memory");
      stage(cur, t + 2);
    }
    cur ^= 1;
  }

#pragma unroll
  for (int mi = 0; mi < 4; ++mi)
#pragma unroll
    for (int ni = 0; ni < 2; ++ni)
#pragma unroll
      for (int r_ = 0; r_ < 4; ++r_) {
        const float v = acc[mi][ni][r_];
        const int row = row0 + wm * 64 + mi * 16 + lg * 4 + r_;
        const int col = col0 + wn * 32 + ni * 16 + lr;
        if constexpr (MODE == 0) {
          const int bb = row >> 11, t = row & 2047;
          const int sec = col >> 10, rem = col & 1023;
          const int h = rem >> 6, d = rem & 63;
          if (sec == 0) {
            Qb[(((size_t)(bb * 16 + h)) * 2048 + t) * 64 + d] =
                (__bf16)(v * 0.1803368801f);  // 1/8 * log2(e)
          } else if (sec == 1) {
            Kb[(((size_t)(bb * 16 + h)) * 2048 + t) * 64 + d] = (__bf16)v;
          } else {
            Vb[(((size_t)(bb * 16 + h)) * 64 + d) * 2048 + t] = (__bf16)v;
          }
        } else {
          Cout[(size_t)row * N + col] = v;
        }
      }
}

// ---------- causal flash attention, swapped-QK^T 32x32, 8-wave slabs ----------
// R12/R16 kernel, byte-identical (verified 97.2us, WRITE 16384, zero spill).
__global__ __launch_bounds__(512, 4) void attn_fwd(
    const __bf16* __restrict__ Q, const __bf16* __restrict__ K,
    const __bf16* __restrict__ Vt, __bf16* __restrict__ O) {
  __shared__ __bf16 Ks[3][64 * 64];  // [kv][d], 16B-chunk ^= row&7
  __shared__ __bf16 Vs[3][64 * 64];  // [d][kv], 16B-chunk ^= row&7
  const int tid = threadIdx.x;
  const int lane = tid & 63;
  const int w = tid >> 6;
  const int hi = lane >> 5;
  const int l31 = lane & 31;
  const int bh = ((blockIdx.y >> 3) << 3) + blockIdx.x;  // same-head -> same XCD
  const int bqj = blockIdx.y & 7;
  const int qj = (bh < 32) ? bqj : 7 - bqj;
  const int q0 = qj * 256;
  const int qw = q0 + w * 32;
  const int qrow = qw + l31;
  const __bf16* Qh = Q + (size_t)bh * 2048 * 64;
  const __bf16* Kh = K + (size_t)bh * 2048 * 64;
  const __bf16* Vth = Vt + (size_t)bh * 64 * 2048;
  const int b = bh >> 4, h = bh & 15;

  const int sr = tid >> 3;
  const int sc = ((tid & 7) ^ (sr & 7)) << 3;

  bf16x8 qf[4];
#pragma unroll
  for (int ks = 0; ks < 4; ++ks)
    qf[ks] = *(const bf16x8*)(Qh + (size_t)qrow * 64 + ks * 16 + hi * 8);

  f32x16 o0 = {}, o1 = {};
  float mrun = -1e30f, lrun = 0.f;

  const int nt = 4 * qj + 4;
  async_copy16(Kh + (size_t)sr * 64 + sc, &Ks[0][tid * 8]);
  async_copy16(Vth + (size_t)sr * 2048 + sc, &Vs[0][tid * 8]);
  if (nt > 1) {
    async_copy16(Kh + (size_t)(64 + sr) * 64 + sc, &Ks[1][tid * 8]);
    async_copy16(Vth + (size_t)sr * 2048 + 64 + sc, &Vs[1][tid * 8]);
  }

  for (int kt = 0; kt < nt; ++kt) {
    const int cur = kt % 3;
    if (kt + 2 < nt) {
      const int nxt = (kt + 2) % 3;
      const int kv0n = (kt + 2) * 64;
      async_copy16(Kh + (size_t)(kv0n + sr) * 64 + sc, &Ks[nxt][tid * 8]);
      async_copy16(Vth + (size_t)sr * 2048 + kv0n + sc, &Vs[nxt][tid * 8]);
      asm volatile("s_waitcnt vmcnt(4)" ::: "memory");
    } else if (kt + 1 < nt) {
      asm volatile("s_waitcnt vmcnt(2)" ::: "memory");
    } else {
      asm volatile("s_waitcnt vmcnt(0)" ::: "memory");
    }
    __builtin_amdgcn_s_barrier();

    const int kv0 = kt * 64;
    if (kv0 <= qw + 31) {
      const __bf16* Kc = &Ks[cur][0];
      const __bf16* Vc = &Vs[cur][0];

      f32x16 s0 = {}, s1 = {};
      __builtin_amdgcn_s_setprio(1);
#pragma unroll
      for (int ks = 0; ks < 4; ++ks) {
        const int g = 2 * ks + hi;
        const int sw = (g ^ (l31 & 7)) << 3;
        const bf16x8 k0 = *(const bf16x8*)(Kc + l31 * 64 + sw);
        const bf16x8 k1 = *(const bf16x8*)(Kc + (32 + l31) * 64 + sw);
        s0 = __builtin_amdgcn_mfma_f32_32x32x16_bf16(k0, qf[ks], s0, 0, 0, 0);
        s1 = __builtin_amdgcn_mfma_f32_32x32x16_bf16(k1, qf[ks], s1, 0, 0, 0);
      }
      __builtin_amdgcn_s_setprio(0);

      if (kv0 + 63 > qw) {
#pragma unroll
        for (int r = 0; r < 16; ++r) {
          const int kvo = (r & 3) + 8 * (r >> 2) + 4 * hi;
          if (kv0 + kvo > qrow)      s0[r] = -1e30f;
          if (kv0 + 32 + kvo > qrow) s1[r] = -1e30f;
        }
      }

      float t[16];
#pragma unroll
      for (int r = 0; r < 16; ++r) t[r] = fmaxf(s0[r], s1[r]);
      float v0 = fmaxf(fmaxf(t[0], t[1]), t[2]);
      float v1 = fmaxf(fmaxf(t[3], t[4]), t[5]);
      float v2 = fmaxf(fmaxf(t[6], t[7]), t[8]);
      float v3 = fmaxf(fmaxf(t[9], t[10]), t[11]);
      float v4 = fmaxf(fmaxf(t[12], t[13]), t[14]);
      float m0 = fmaxf(fmaxf(v0, v1), v2);
      float m1 = fmaxf(fmaxf(v3, v4), t[15]);
      float pm = fmaxf(m0, m1);
      pm = fmaxf(pm, __shfl_xor(pm, 32));

      if (!__all(pm <= mrun + 8.f)) {
        const float nm = fmaxf(mrun, pm);
        const float alpha = exp2f(mrun - nm);
        mrun = nm;
        lrun *= alpha;
#pragma unroll
        for (int r = 0; r < 16; ++r) { o0[r] *= alpha; o1[r] *= alpha; }
      }

      float u[16];
#pragma unroll
      for (int r = 0; r < 16; ++r) {
        s0[r] = exp2f(s0[r] - mrun);
        s1[r] = exp2f(s1[r] - mrun);
        u[r] = s0[r] + s1[r];
      }
#pragma unroll
      for (int st = 8; st >= 1; st >>= 1)
#pragma unroll
        for (int r = 0; r < st; ++r) u[r] += u[r + st];
      lrun += u[0] + __shfl_xor(u[0], 32);

      unsigned int pk[16];
#pragma unroll
      for (int t2 = 0; t2 < 8; ++t2) {
        pk[t2]     = pack2(s0[2 * t2], s0[2 * t2 + 1]);
        pk[8 + t2] = pack2(s1[2 * t2], s1[2 * t2 + 1]);
      }

      __builtin_amdgcn_s_setprio(1);
#pragma unroll
      for (int ks2 = 0; ks2 < 4; ++ks2) {
        const int bidx = (ks2 >> 1) * 8 + (ks2 & 1) * 4;
        const unsigned int send0 = hi ? pk[bidx]     : pk[bidx + 2];
        const unsigned int send1 = hi ? pk[bidx + 1] : pk[bidx + 3];
        const unsigned int rr0 = __shfl_xor(send0, 32);
        const unsigned int rr1 = __shfl_xor(send1, 32);
        const unsigned int own0 = hi ? pk[bidx + 2] : pk[bidx];
        const unsigned int own1 = hi ? pk[bidx + 3] : pk[bidx + 1];
        u32x4 wds;
        wds.x = hi ? rr0 : own0;
        wds.y = hi ? rr1 : own1;
        wds.z = hi ? own0 : rr0;
        wds.w = hi ? own1 : rr1;
        const bf16x8 pfr = __builtin_bit_cast(bf16x8, wds);
        const int gv = 2 * ks2 + hi;
        const int sw = (gv ^ (l31 & 7)) << 3;
        const bf16x8 vv0 = *(const bf16x8*)(Vc + l31 * 64 + sw);
        const bf16x8 vv1 = *(const bf16x8*)(Vc + (32 + l31) * 64 + sw);
        o0 = __builtin_amdgcn_mfma_f32_32x32x16_bf16(vv0, pfr, o0, 0, 0, 0);
        o1 = __builtin_amdgcn_mfma_f32_32x32x16_bf16(vv1, pfr, o1, 0, 0, 0);
      }
      __builtin_amdgcn_s_setprio(0);
    }
    __builtin_amdgcn_s_barrier();
  }

  const float linv = 1.0f / lrun;
  __bf16* base = O + ((size_t)(b * 2048 + qrow)) * 1024 + h * 64;
#pragma unroll
  for (int rg = 0; rg < 4; ++rg) {
    bf16x4 ov0, ov1;
#pragma unroll
    for (int i = 0; i < 4; ++i) {
      ov0[i] = (__bf16)(o0[rg * 4 + i] * linv);
      ov1[i] = (__bf16)(o1[rg * 4 + i] * linv);
    }
    *(bf16x4*)(base + rg * 8 + hi * 4)      = ov0;
    *(bf16x4*)(base + 32 + rg * 8 + hi * 4) = ov1;
  }
}

// ---------- launch ----------
extern "C" void kernel_launch(void* const* d_in, const int* in_sizes, int n_in,
                              void* d_out, int out_size, void* d_ws, size_t ws_size,
                              hipStream_t stream) {
  const float* x    = (const float*)d_in[0];  // [4,2048,1024]
  const float* Wqkv = (const float*)d_in[1];  // [1024,3072]
  const float* Wout = (const float*)d_in[2];  // [1024,1024]
  float* out = (float*)d_out;                 // [4,2048,1024] fp32

  char* ws = (char*)d_ws;
  __bf16* xb     = (__bf16*)(ws);
  __bf16* wqkvt  = (__bf16*)(ws + 16777216);
  __bf16* woutt  = (__bf16*)(ws + 23068672);
  __bf16* Qb     = (__bf16*)(ws + 25165824);
  __bf16* Kb     = (__bf16*)(ws + 41943040);
  __bf16* Vtb    = (__bf16*)(ws + 58720256);  // [B,H,64,T]
  __bf16* attnb  = (__bf16*)(ws + 75497472);

  prep<<<12288, 256, 0, stream>>>(x, xb, Wqkv, wqkvt, Wout, woutt);

  gemmp8<0, 1, 24><<<dim3(24, 64), 512, 0, stream>>>(
      xb, wqkvt, Qb, Kb, Vtb, nullptr, 1024, 3072);
  attn_fwd<<<dim3(8, 64), 512, 0, stream>>>(Qb, Kb, Vtb, attnb);
  gemmp8<1, 1, 8><<<dim3(8, 64), 512, 0, stream>>>(
      attnb, woutt, nullptr, nullptr, nullptr, out, 1024, 1024);
}

// Round 20
// 198.536 us; speedup vs baseline: 1.0674x; 1.0674x over previous
//
#include <hip/hip_runtime.h>

// ---------- types ----------
typedef __attribute__((ext_vector_type(8)))  __bf16 bf16x8;
typedef __attribute__((ext_vector_type(4)))  __bf16 bf16x4;
typedef __attribute__((ext_vector_type(4)))  float  f32x4;
typedef __attribute__((ext_vector_type(16))) float  f32x16;
typedef __attribute__((ext_vector_type(4)))  unsigned int u32x4;

#define DEVINL __device__ __forceinline__

DEVINL void async_copy16(const __bf16* g, __bf16* l) {
  __builtin_amdgcn_global_load_lds(
      (__attribute__((address_space(1))) void*)(g),
      (__attribute__((address_space(3))) void*)(l), 16, 0, 0);
}

DEVINL unsigned int pack2(float a, float b) {
  unsigned short ua = __builtin_bit_cast(unsigned short, (__bf16)a);
  unsigned short ub = __builtin_bit_cast(unsigned short, (__bf16)b);
  return (unsigned int)ua | ((unsigned int)ub << 16);
}

// ---------- fused prologue: x cvt + both weight transposes, ONE dispatch ----
__global__ __launch_bounds__(256) void prep(
    const float* __restrict__ x, __bf16* __restrict__ xb,
    const float* __restrict__ Wqkv, __bf16* __restrict__ wqkvt,
    const float* __restrict__ Wout, __bf16* __restrict__ woutt) {
  const int id = blockIdx.x;
  if (id < 8192) {
    const int i = (id * 256 + threadIdx.x) * 4;
    const float4 f = *(const float4*)(x + i);
    bf16x4 ov;
    ov.x = (__bf16)f.x; ov.y = (__bf16)f.y;
    ov.z = (__bf16)f.z; ov.w = (__bf16)f.w;
    *(bf16x4*)(xb + i) = ov;
  } else {
    __shared__ float tile[32][33];
    const float* W;
    __bf16* Wt;
    int N, bx, by;
    if (id < 11264) {
      const int r = id - 8192;
      W = Wqkv; Wt = wqkvt; N = 3072; bx = r % 96; by = r / 96;
    } else {
      const int r = id - 11264;
      W = Wout; Wt = woutt; N = 1024; bx = r & 31; by = r >> 5;
    }
    const int tx = threadIdx.x & 31, ty = threadIdx.x >> 5;
    const int kb = by * 32, nb = bx * 32;
#pragma unroll
    for (int j = ty; j < 32; j += 8)
      tile[j][tx] = W[(size_t)(kb + j) * N + nb + tx];
    __syncthreads();
#pragma unroll
    for (int j = ty; j < 32; j += 8)
      Wt[(size_t)(nb + j) * 1024 + kb + tx] = (__bf16)tile[tx][j];
  }
}

// ---------- 8-wave 128x128 counted-vmcnt GEMM (R12/R14/R18, verified) ----------
// Monolithic compute block (R19's 4-sub-phase split REGRESSED: 5 barriers/tile
// lock-stepped waves through tiny quanta, dur ~2x — barrier subdivision
// without the true 8-phase half-tile staging overlap is net-negative).
template <int MODE, int XCDSWZ, int GX>
__global__ __launch_bounds__(512, 2) void gemmp8(
    const __bf16* __restrict__ A, const __bf16* __restrict__ Bt,
    __bf16* __restrict__ Qb, __bf16* __restrict__ Kb, __bf16* __restrict__ Vb,
    float* __restrict__ Cout, int K, int N) {
  constexpr int BM = 128, BN = 128;
  __shared__ __bf16 As[2][BM * 64];
  __shared__ __bf16 Bs[2][BN * 64];
  const int tid = threadIdx.x;
  const int lane = tid & 63;
  const int w = tid >> 6;
  const int wm = w >> 2, wn = w & 3;
  const int lr = lane & 15, lg = lane >> 4;

  int bx = blockIdx.x, by = blockIdx.y;
  if constexpr (XCDSWZ) {
    const int nwg = GX * gridDim.y;
    const int chunk = nwg >> 3;
    const int id = by * GX + bx;
    const int swz = (id & 7) * chunk + (id >> 3);
    bx = swz % GX;
    by = swz / GX;
  }
  const int row0 = by * BM;
  const int col0 = bx * BN;

  f32x4 acc[4][2] = {};

  auto stage = [&](int buf, int kt) {
    const int ko = kt * 64;
#pragma unroll
    for (int rd = 0; rd < 2; ++rd) {
      const int slot = rd * 512 + tid;
      const int r = slot >> 3, c = slot & 7;
      async_copy16(A + (size_t)(row0 + r) * K + ko + ((c ^ (r & 7)) << 3),
                   &As[buf][slot * 8]);
    }
#pragma unroll
    for (int rd = 0; rd < 2; ++rd) {
      const int slot = rd * 512 + tid;
      const int r = slot >> 3, c = slot & 7;
      async_copy16(Bt + (size_t)(col0 + r) * K + ko + ((c ^ (r & 7)) << 3),
                   &Bs[buf][slot * 8]);
    }
  };

  auto compute = [&](int buf) {
    bf16x8 af[4][2], bfr[2][2];
#pragma unroll
    for (int mi = 0; mi < 4; ++mi)
#pragma unroll
      for (int ks = 0; ks < 2; ++ks) {
        const int r = wm * 64 + mi * 16 + lr;
        af[mi][ks] =
            *(const bf16x8*)(&As[buf][r * 64 + (((ks * 4 + lg) ^ (r & 7)) << 3)]);
      }
#pragma unroll
    for (int ni = 0; ni < 2; ++ni)
#pragma unroll
      for (int ks = 0; ks < 2; ++ks) {
        const int r = wn * 32 + ni * 16 + lr;
        bfr[ni][ks] =
            *(const bf16x8*)(&Bs[buf][r * 64 + (((ks * 4 + lg) ^ (r & 7)) << 3)]);
      }
    __builtin_amdgcn_s_setprio(1);
#pragma unroll
    for (int mi = 0; mi < 4; ++mi)
#pragma unroll
      for (int ni = 0; ni < 2; ++ni)
#pragma unroll
        for (int ks = 0; ks < 2; ++ks)
          acc[mi][ni] = __builtin_amdgcn_mfma_f32_16x16x32_bf16(
              af[mi][ks], bfr[ni][ks], acc[mi][ni], 0, 0, 0);
    __builtin_amdgcn_s_setprio(0);
  };

  const int nkt = K / 64;
  stage(0, 0);
  if (nkt > 1) stage(1, 1);
  int cur = 0;
#pragma unroll 1
  for (int t = 0; t < nkt; ++t) {
    if (t + 1 < nkt)
      asm volatile("s_waitcnt vmcnt(4)" ::: "memory");
    else
      asm volatile("s_waitcnt vmcnt(0)" ::: "memory");
    __builtin_amdgcn_s_barrier();
    asm volatile("" ::: "memory");
    compute(cur);
    if (t + 2 < nkt) {
      __builtin_amdgcn_s_barrier();
      asm volatile("" ::: "memory");
      stage(cur, t + 2);
    }
    cur ^= 1;
  }

#pragma unroll
  for (int mi = 0; mi < 4; ++mi)
#pragma unroll
    for (int ni = 0; ni < 2; ++ni)
#pragma unroll
      for (int r_ = 0; r_ < 4; ++r_) {
        const float v = acc[mi][ni][r_];
        const int row = row0 + wm * 64 + mi * 16 + lg * 4 + r_;
        const int col = col0 + wn * 32 + ni * 16 + lr;
        if constexpr (MODE == 0) {
          const int bb = row >> 11, t = row & 2047;
          const int sec = col >> 10, rem = col & 1023;
          const int h = rem >> 6, d = rem & 63;
          if (sec == 0) {
            Qb[(((size_t)(bb * 16 + h)) * 2048 + t) * 64 + d] =
                (__bf16)(v * 0.1803368801f);  // 1/8 * log2(e)
          } else if (sec == 1) {
            Kb[(((size_t)(bb * 16 + h)) * 2048 + t) * 64 + d] = (__bf16)v;
          } else {
            Vb[(((size_t)(bb * 16 + h)) * 64 + d) * 2048 + t] = (__bf16)v;
          }
        } else {
          Cout[(size_t)row * N + col] = v;
        }
      }
}

// ---------- causal flash attention, swapped-QK^T 32x32, 8-wave slabs ----------
// R12/R16/R18 kernel, byte-identical (verified 97.2us, WRITE 16384, no spill).
__global__ __launch_bounds__(512, 4) void attn_fwd(
    const __bf16* __restrict__ Q, const __bf16* __restrict__ K,
    const __bf16* __restrict__ Vt, __bf16* __restrict__ O) {
  __shared__ __bf16 Ks[3][64 * 64];  // [kv][d], 16B-chunk ^= row&7
  __shared__ __bf16 Vs[3][64 * 64];  // [d][kv], 16B-chunk ^= row&7
  const int tid = threadIdx.x;
  const int lane = tid & 63;
  const int w = tid >> 6;
  const int hi = lane >> 5;
  const int l31 = lane & 31;
  const int bh = ((blockIdx.y >> 3) << 3) + blockIdx.x;  // same-head -> same XCD
  const int bqj = blockIdx.y & 7;
  const int qj = (bh < 32) ? bqj : 7 - bqj;
  const int q0 = qj * 256;
  const int qw = q0 + w * 32;
  const int qrow = qw + l31;
  const __bf16* Qh = Q + (size_t)bh * 2048 * 64;
  const __bf16* Kh = K + (size_t)bh * 2048 * 64;
  const __bf16* Vth = Vt + (size_t)bh * 64 * 2048;
  const int b = bh >> 4, h = bh & 15;

  const int sr = tid >> 3;
  const int sc = ((tid & 7) ^ (sr & 7)) << 3;

  bf16x8 qf[4];
#pragma unroll
  for (int ks = 0; ks < 4; ++ks)
    qf[ks] = *(const bf16x8*)(Qh + (size_t)qrow * 64 + ks * 16 + hi * 8);

  f32x16 o0 = {}, o1 = {};
  float mrun = -1e30f, lrun = 0.f;

  const int nt = 4 * qj + 4;
  async_copy16(Kh + (size_t)sr * 64 + sc, &Ks[0][tid * 8]);
  async_copy16(Vth + (size_t)sr * 2048 + sc, &Vs[0][tid * 8]);
  if (nt > 1) {
    async_copy16(Kh + (size_t)(64 + sr) * 64 + sc, &Ks[1][tid * 8]);
    async_copy16(Vth + (size_t)sr * 2048 + 64 + sc, &Vs[1][tid * 8]);
  }

  for (int kt = 0; kt < nt; ++kt) {
    const int cur = kt % 3;
    if (kt + 2 < nt) {
      const int nxt = (kt + 2) % 3;
      const int kv0n = (kt + 2) * 64;
      async_copy16(Kh + (size_t)(kv0n + sr) * 64 + sc, &Ks[nxt][tid * 8]);
      async_copy16(Vth + (size_t)sr * 2048 + kv0n + sc, &Vs[nxt][tid * 8]);
      asm volatile("s_waitcnt vmcnt(4)" ::: "memory");
    } else if (kt + 1 < nt) {
      asm volatile("s_waitcnt vmcnt(2)" ::: "memory");
    } else {
      asm volatile("s_waitcnt vmcnt(0)" ::: "memory");
    }
    __builtin_amdgcn_s_barrier();

    const int kv0 = kt * 64;
    if (kv0 <= qw + 31) {
      const __bf16* Kc = &Ks[cur][0];
      const __bf16* Vc = &Vs[cur][0];

      f32x16 s0 = {}, s1 = {};
      __builtin_amdgcn_s_setprio(1);
#pragma unroll
      for (int ks = 0; ks < 4; ++ks) {
        const int g = 2 * ks + hi;
        const int sw = (g ^ (l31 & 7)) << 3;
        const bf16x8 k0 = *(const bf16x8*)(Kc + l31 * 64 + sw);
        const bf16x8 k1 = *(const bf16x8*)(Kc + (32 + l31) * 64 + sw);
        s0 = __builtin_amdgcn_mfma_f32_32x32x16_bf16(k0, qf[ks], s0, 0, 0, 0);
        s1 = __builtin_amdgcn_mfma_f32_32x32x16_bf16(k1, qf[ks], s1, 0, 0, 0);
      }
      __builtin_amdgcn_s_setprio(0);

      if (kv0 + 63 > qw) {
#pragma unroll
        for (int r = 0; r < 16; ++r) {
          const int kvo = (r & 3) + 8 * (r >> 2) + 4 * hi;
          if (kv0 + kvo > qrow)      s0[r] = -1e30f;
          if (kv0 + 32 + kvo > qrow) s1[r] = -1e30f;
        }
      }

      float t[16];
#pragma unroll
      for (int r = 0; r < 16; ++r) t[r] = fmaxf(s0[r], s1[r]);
      float v0 = fmaxf(fmaxf(t[0], t[1]), t[2]);
      float v1 = fmaxf(fmaxf(t[3], t[4]), t[5]);
      float v2 = fmaxf(fmaxf(t[6], t[7]), t[8]);
      float v3 = fmaxf(fmaxf(t[9], t[10]), t[11]);
      float v4 = fmaxf(fmaxf(t[12], t[13]), t[14]);
      float m0 = fmaxf(fmaxf(v0, v1), v2);
      float m1 = fmaxf(fmaxf(v3, v4), t[15]);
      float pm = fmaxf(m0, m1);
      pm = fmaxf(pm, __shfl_xor(pm, 32));

      if (!__all(pm <= mrun + 8.f)) {
        const float nm = fmaxf(mrun, pm);
        const float alpha = exp2f(mrun - nm);
        mrun = nm;
        lrun *= alpha;
#pragma unroll
        for (int r = 0; r < 16; ++r) { o0[r] *= alpha; o1[r] *= alpha; }
      }

      float u[16];
#pragma unroll
      for (int r = 0; r < 16; ++r) {
        s0[r] = exp2f(s0[r] - mrun);
        s1[r] = exp2f(s1[r] - mrun);
        u[r] = s0[r] + s1[r];
      }
#pragma unroll
      for (int st = 8; st >= 1; st >>= 1)
#pragma unroll
        for (int r = 0; r < st; ++r) u[r] += u[r + st];
      lrun += u[0] + __shfl_xor(u[0], 32);

      unsigned int pk[16];
#pragma unroll
      for (int t2 = 0; t2 < 8; ++t2) {
        pk[t2]     = pack2(s0[2 * t2], s0[2 * t2 + 1]);
        pk[8 + t2] = pack2(s1[2 * t2], s1[2 * t2 + 1]);
      }

      __builtin_amdgcn_s_setprio(1);
#pragma unroll
      for (int ks2 = 0; ks2 < 4; ++ks2) {
        const int bidx = (ks2 >> 1) * 8 + (ks2 & 1) * 4;
        const unsigned int send0 = hi ? pk[bidx]     : pk[bidx + 2];
        const unsigned int send1 = hi ? pk[bidx + 1] : pk[bidx + 3];
        const unsigned int rr0 = __shfl_xor(send0, 32);
        const unsigned int rr1 = __shfl_xor(send1, 32);
        const unsigned int own0 = hi ? pk[bidx + 2] : pk[bidx];
        const unsigned int own1 = hi ? pk[bidx + 3] : pk[bidx + 1];
        u32x4 wds;
        wds.x = hi ? rr0 : own0;
        wds.y = hi ? rr1 : own1;
        wds.z = hi ? own0 : rr0;
        wds.w = hi ? own1 : rr1;
        const bf16x8 pfr = __builtin_bit_cast(bf16x8, wds);
        const int gv = 2 * ks2 + hi;
        const int sw = (gv ^ (l31 & 7)) << 3;
        const bf16x8 vv0 = *(const bf16x8*)(Vc + l31 * 64 + sw);
        const bf16x8 vv1 = *(const bf16x8*)(Vc + (32 + l31) * 64 + sw);
        o0 = __builtin_amdgcn_mfma_f32_32x32x16_bf16(vv0, pfr, o0, 0, 0, 0);
        o1 = __builtin_amdgcn_mfma_f32_32x32x16_bf16(vv1, pfr, o1, 0, 0, 0);
      }
      __builtin_amdgcn_s_setprio(0);
    }
    __builtin_amdgcn_s_barrier();
  }

  const float linv = 1.0f / lrun;
  __bf16* base = O + ((size_t)(b * 2048 + qrow)) * 1024 + h * 64;
#pragma unroll
  for (int rg = 0; rg < 4; ++rg) {
    bf16x4 ov0, ov1;
#pragma unroll
    for (int i = 0; i < 4; ++i) {
      ov0[i] = (__bf16)(o0[rg * 4 + i] * linv);
      ov1[i] = (__bf16)(o1[rg * 4 + i] * linv);
    }
    *(bf16x4*)(base + rg * 8 + hi * 4)      = ov0;
    *(bf16x4*)(base + 32 + rg * 8 + hi * 4) = ov1;
  }
}

// ---------- launch ----------
extern "C" void kernel_launch(void* const* d_in, const int* in_sizes, int n_in,
                              void* d_out, int out_size, void* d_ws, size_t ws_size,
                              hipStream_t stream) {
  const float* x    = (const float*)d_in[0];  // [4,2048,1024]
  const float* Wqkv = (const float*)d_in[1];  // [1024,3072]
  const float* Wout = (const float*)d_in[2];  // [1024,1024]
  float* out = (float*)d_out;                 // [4,2048,1024] fp32

  char* ws = (char*)d_ws;
  __bf16* xb     = (__bf16*)(ws);
  __bf16* wqkvt  = (__bf16*)(ws + 16777216);
  __bf16* woutt  = (__bf16*)(ws + 23068672);
  __bf16* Qb     = (__bf16*)(ws + 25165824);
  __bf16* Kb     = (__bf16*)(ws + 41943040);
  __bf16* Vtb    = (__bf16*)(ws + 58720256);  // [B,H,64,T]
  __bf16* attnb  = (__bf16*)(ws + 75497472);

  prep<<<12288, 256, 0, stream>>>(x, xb, Wqkv, wqkvt, Wout, woutt);

  gemmp8<0, 1, 24><<<dim3(24, 64), 512, 0, stream>>>(
      xb, wqkvt, Qb, Kb, Vtb, nullptr, 1024, 3072);
  attn_fwd<<<dim3(8, 64), 512, 0, stream>>>(Qb, Kb, Vtb, attnb);
  gemmp8<1, 1, 8><<<dim3(8, 64), 512, 0, stream>>>(
      attnb, woutt, nullptr, nullptr, nullptr, out, 1024, 1024);
}